// Round 10
// baseline (18221.370 us; speedup 1.0000x reference)
//
#include <hip/hip_runtime.h>
#include <hip/hip_bf16.h>

#define S_LEN 8192
#define CLEN 16
#define WDIM 256
#define CDIM 64
#define CHID 128
#define WHID 512
#define GDIM 2048   // 4*WHID
#define NTAG 64
#define KDIM 384    // WDIM + CHID
#define NWG 32      // recurrence workgroups
#define NCHAR_BLK 512            // S_LEN/16
#define NGEMM_BLK 4096           // 128 M-tiles x 32 N-tiles
#define GRID_TOTAL (NWG + NCHAR_BLK + NGEMM_BLK)

typedef unsigned long long u64;

__device__ __forceinline__ float sigmoidf_(float x) {
  return 1.0f / (1.0f + __expf(-x));
}
__device__ __forceinline__ float tanhf_(float x) {
  // safe tanh: 1 - 2/(e^{2x}+1); correct limits at +-inf without NaN
  return 1.0f - 2.0f / (__expf(2.0f * x) + 1.0f);
}

// ---------------------------------------------------------------------------
// Fused kernel: block-role split.
//   blocks [0,32):        sequential word LSTM (R3-verbatim structure, proven
//                         13.88 ms) + once-per-64-steps Gx-tile gate.
//   blocks [32,544):      char LSTM, 16 words/block; release cf_cnt[group].
//   blocks [544,4640):    Gx GEMM 64x64 tiles in M-order; wait cf_cnt[m]==4,
//                         release gx_cnt[m] when tile done.
// The 224 CUs that previously idled during the 14 ms recurrence now absorb
// all setup work; the recurrence only ever waits on gx_cnt during the first
// ~2 tiles (ramp).
// Liveness: char never waits; gemm waits only on char (guaranteed); the
// recurrence waits on gemm (guaranteed) and on its own R3-proven h-sync.
// ---------------------------------------------------------------------------
__global__ __launch_bounds__(256, 1)
void fused_kernel(const int* __restrict__ x, const int* __restrict__ chars,
                  const int* __restrict__ lengths,
                  const float* __restrict__ word_emb,
                  const float* __restrict__ char_emb,
                  const float* __restrict__ cWih, const float* __restrict__ cWhh,
                  const float* __restrict__ cbih, const float* __restrict__ cbhh,
                  const float* __restrict__ wWih, const float* __restrict__ wWhh,
                  const float* __restrict__ wbih, const float* __restrict__ wbhh,
                  float* __restrict__ char_feat, float* __restrict__ Gx,
                  float* __restrict__ hs, u64* hbuf,
                  int* cf_cnt, int* gx_cnt)
{
  __shared__ __align__(16) char smem[17408];
  const int tid = threadIdx.x;
  const int bid = blockIdx.x;

  if (bid < NWG) {
    // ================= ROLE A: sequential word LSTM (R3 verbatim) ==========
    float* h_lds = (float*)smem;                       // 512 f
    float(*red)[256] = (float(*)[256])(smem + 2048);   // [2][256]
    const int wg = bid;
    const int cc = tid >> 6;
    const int lane = tid & 63;
    const int kb = cc * 128;
    const int grow = (lane >> 4) * WHID + wg * 16 + (lane & 15);

    // per-lane weight chunk (R3 codegen: compiler streams these from L2
    // inside the loop -- measured faster than LDS-resident at 1 WG/CU)
    const int growL = (lane >> 4) * WHID + wg * 16 + (lane & 15);
    float wl[128];
    {
      const float* wsrc = wWhh + (size_t)growL * WHID + kb;
#pragma unroll
      for (int k = 0; k < 128; ++k) wl[k] = wsrc[k];
    }

    float c_state = 0.f;   // lanes<16 of wave 0

    for (int t = 0; t < S_LEN; ++t) {
      const int par = t & 1;
      float gxv = 0.f;
      if (tid < 64) {
        if ((t & 63) == 0) {   // Gx tile gate (passes instantly after ramp)
          const int mt = t >> 6;
          while (__hip_atomic_load(&gx_cnt[mt], __ATOMIC_ACQUIRE,
                                   __HIP_MEMORY_SCOPE_AGENT) < 32) {}
        }
        gxv = Gx[(size_t)t * GDIM + grow];   // issued before poll
      }
      // poll own 2 tagged slots (atomic u64: tag+value arrive together)
      float v0 = 0.f, v1 = 0.f;
      if (t > 0) {
        const u64* ps = hbuf + (size_t)par * WHID + kb + 2 * lane;
        const unsigned want = (unsigned)t;
        u64 a, b;
        do {
          a = __hip_atomic_load(ps + 0, __ATOMIC_RELAXED, __HIP_MEMORY_SCOPE_AGENT);
          b = __hip_atomic_load(ps + 1, __ATOMIC_RELAXED, __HIP_MEMORY_SCOPE_AGENT);
        } while (((unsigned)(a >> 32) != want) | ((unsigned)(b >> 32) != want));
        v0 = __uint_as_float((unsigned)a);
        v1 = __uint_as_float((unsigned)b);
      }
      *(float2*)(&h_lds[kb + 2 * lane]) = make_float2(v0, v1);
      __threadfence_block();
      float acc = 0.f;
#pragma unroll
      for (int g = 0; g < 32; ++g) {
        float4 hv = *(const float4*)(&h_lds[kb + 4 * g]);
        acc = fmaf(wl[4 * g + 0], hv.x, acc);
        acc = fmaf(wl[4 * g + 1], hv.y, acc);
        acc = fmaf(wl[4 * g + 2], hv.z, acc);
        acc = fmaf(wl[4 * g + 3], hv.w, acc);
      }
      red[par][tid] = acc;
      __syncthreads();   // the ONLY barrier per step
      if (tid < 64) {
        const float* rp = red[par];
        float s = rp[tid] + rp[64 + tid] + rp[128 + tid] + rp[192 + tid] + gxv;
        float act = ((tid >> 4) == 2) ? tanhf_(s) : sigmoidf_(s);
        int jj = tid & 15;
        float iv = __shfl(act, jj);
        float fv = __shfl(act, 16 + jj);
        float gv = __shfl(act, 32 + jj);
        float ov = __shfl(act, 48 + jj);
        if (tid < 16) {
          c_state = fv * c_state + iv * gv;
          float hv = ov * tanhf_(c_state);
          const int hidx = wg * 16 + tid;
          const u64 pkt =
              ((u64)(unsigned)(t + 1) << 32) | (u64)__float_as_uint(hv);
          (void)__hip_atomic_exchange(
              &hbuf[(size_t)((t + 1) & 1) * WHID + hidx], pkt,
              __ATOMIC_RELAXED, __HIP_MEMORY_SCOPE_AGENT);
          hs[(size_t)t * WHID + hidx] = hv;
        }
      }
    }

  } else if (bid < NWG + NCHAR_BLK) {
    // ================= ROLE B: char LSTM (16 words/block) ===================
    float(*xs)[CDIM] = (float(*)[CDIM])smem;                 // 4096 B
    float(*hsm)[CHID] = (float(*)[CHID])(smem + 4096);       // 8192 B
    int* cidx = (int*)(smem + 12288);
    int* lens = (int*)(smem + 12352);
    const int grp = tid >> 7;
    const int j = tid & 127;
    const int cb = bid - NWG;
    const int wb = cb * 16;

    for (int i = tid; i < 16 * CHID; i += 256) (&hsm[0][0])[i] = 0.f;
    if (tid < 16) lens[tid] = lengths[wb + tid];
    float c[8];
#pragma unroll
    for (int w = 0; w < 8; ++w) c[w] = 0.f;
    const float bi = cbih[j] + cbhh[j];
    const float bf = cbih[CHID + j] + cbhh[CHID + j];
    const float bg = cbih[2 * CHID + j] + cbhh[2 * CHID + j];
    const float bo = cbih[3 * CHID + j] + cbhh[3 * CHID + j];

    for (int t = 0; t < CLEN; ++t) {
      __syncthreads();
      if (tid < 16) cidx[tid] = chars[(wb + tid) * CLEN + t];
      __syncthreads();
      {
        int e = tid * 4;
        int wi = e >> 6;
        int k = e & 63;
        const float4 v = *(const float4*)(char_emb + (size_t)cidx[wi] * CDIM + k);
        *(float4*)(&xs[wi][k]) = v;
      }
      __syncthreads();
      float ai[8], af[8], ag[8], ao[8];
#pragma unroll
      for (int w = 0; w < 8; ++w) { ai[w] = bi; af[w] = bf; ag[w] = bg; ao[w] = bo; }
      for (int k = 0; k < CDIM; k += 4) {
        float4 w0 = *(const float4*)(cWih + (size_t)j * CDIM + k);
        float4 w1 = *(const float4*)(cWih + (size_t)(CHID + j) * CDIM + k);
        float4 w2 = *(const float4*)(cWih + (size_t)(2 * CHID + j) * CDIM + k);
        float4 w3 = *(const float4*)(cWih + (size_t)(3 * CHID + j) * CDIM + k);
#pragma unroll
        for (int s = 0; s < 4; ++s) {
          float wiv = (&w0.x)[s], wfv = (&w1.x)[s], wgv = (&w2.x)[s], wov = (&w3.x)[s];
#pragma unroll
          for (int w = 0; w < 8; ++w) {
            float xv = xs[grp * 8 + w][k + s];
            ai[w] = fmaf(wiv, xv, ai[w]);
            af[w] = fmaf(wfv, xv, af[w]);
            ag[w] = fmaf(wgv, xv, ag[w]);
            ao[w] = fmaf(wov, xv, ao[w]);
          }
        }
      }
      for (int k = 0; k < CHID; k += 4) {
        float4 w0 = *(const float4*)(cWhh + (size_t)j * CHID + k);
        float4 w1 = *(const float4*)(cWhh + (size_t)(CHID + j) * CHID + k);
        float4 w2 = *(const float4*)(cWhh + (size_t)(2 * CHID + j) * CHID + k);
        float4 w3 = *(const float4*)(cWhh + (size_t)(3 * CHID + j) * CHID + k);
#pragma unroll
        for (int s = 0; s < 4; ++s) {
          float wiv = (&w0.x)[s], wfv = (&w1.x)[s], wgv = (&w2.x)[s], wov = (&w3.x)[s];
#pragma unroll
          for (int w = 0; w < 8; ++w) {
            float hv = hsm[grp * 8 + w][k + s];
            ai[w] = fmaf(wiv, hv, ai[w]);
            af[w] = fmaf(wfv, hv, af[w]);
            ag[w] = fmaf(wgv, hv, ag[w]);
            ao[w] = fmaf(wov, hv, ao[w]);
          }
        }
      }
      __syncthreads();
#pragma unroll
      for (int w = 0; w < 8; ++w) {
        if (t < lens[grp * 8 + w]) {
          float iv = sigmoidf_(ai[w]);
          float fv = sigmoidf_(af[w]);
          float gv = tanhf_(ag[w]);
          float ov = sigmoidf_(ao[w]);
          c[w] = fv * c[w] + iv * gv;
          hsm[grp * 8 + w][j] = ov * tanhf_(c[w]);
        }
      }
    }
#pragma unroll
    for (int w = 0; w < 8; ++w)
      char_feat[(size_t)(wb + grp * 8 + w) * CHID + j] = c[w];
    __threadfence();     // make this thread's cf stores agent-visible
    __syncthreads();     // all threads' fences done
    if (tid == 0)
      (void)__hip_atomic_fetch_add(&cf_cnt[cb >> 2], 1, __ATOMIC_RELEASE,
                                   __HIP_MEMORY_SCOPE_AGENT);

  } else {
    // ================= ROLE C: Gx GEMM 64x64 tile ===========================
    float(*As)[65] = (float(*)[65])smem;                   // 8320 B
    float(*Bs)[65] = (float(*)[65])(smem + 8320);          // 8320 B
    int* xidx = (int*)(smem + 16640);                      // 256 B
    const int bid2 = bid - NWG - NCHAR_BLK;
    const int m = bid2 >> 5;           // M-tiles complete in t-order
    const int n = bid2 & 31;
    const int m0 = m * 64;
    const int n0 = n * 64;
    const int tx = tid & 15, ty = tid >> 4;

    // wait for the 4 char blocks feeding rows [m0, m0+64)
    if (tid == 0) {
      while (__hip_atomic_load(&cf_cnt[m], __ATOMIC_ACQUIRE,
                               __HIP_MEMORY_SCOPE_AGENT) < 4) {}
    }
    __syncthreads();
    if (tid < 64) xidx[tid] = x[m0 + tid];

    float acc[4][4] = {};
    for (int k0 = 0; k0 < KDIM; k0 += 32) {
      __syncthreads();
      {
        int i = tid >> 5;
        int kk = tid & 31;
#pragma unroll
        for (int l = 0; l < 8; ++l) {
          int row = i + l * 8;
          int k = k0 + kk;
          int tt = m0 + row;
          float v = (k < WDIM) ? word_emb[(size_t)xidx[row] * WDIM + k]
                               : char_feat[(size_t)tt * CHID + (k - WDIM)];
          As[kk][row] = v;
        }
      }
      {
        int jjj = tid >> 5;
        int kk = tid & 31;
#pragma unroll
        for (int l = 0; l < 8; ++l) {
          int col = jjj + l * 8;
          Bs[kk][col] = wWih[(size_t)(n0 + col) * KDIM + k0 + kk];
        }
      }
      __syncthreads();
#pragma unroll
      for (int kk = 0; kk < 32; ++kk) {
        float a[4], b[4];
#pragma unroll
        for (int mm = 0; mm < 4; ++mm) a[mm] = As[kk][ty * 4 + mm];
#pragma unroll
        for (int nn = 0; nn < 4; ++nn) b[nn] = Bs[kk][tx * 4 + nn];
#pragma unroll
        for (int mm = 0; mm < 4; ++mm)
#pragma unroll
          for (int nn = 0; nn < 4; ++nn)
            acc[mm][nn] = fmaf(a[mm], b[nn], acc[mm][nn]);
      }
    }
#pragma unroll
    for (int nn = 0; nn < 4; ++nn) {
      int g = n0 + tx * 4 + nn;
      float bias = wbih[g] + wbhh[g];
#pragma unroll
      for (int mm = 0; mm < 4; ++mm) {
        int tt = m0 + ty * 4 + mm;
        Gx[(size_t)tt * GDIM + g] = acc[mm][nn] + bias;
      }
    }
    __threadfence();     // Gx stores agent-visible
    __syncthreads();
    if (tid == 0)
      (void)__hip_atomic_fetch_add(&gx_cnt[m], 1, __ATOMIC_RELEASE,
                                   __HIP_MEMORY_SCOPE_AGENT);
  }
}

// ---------------------------------------------------------------------------
// K4: logits + log_softmax. One 64-lane wave per row t; lane = tag.
// ---------------------------------------------------------------------------
__global__ __launch_bounds__(256)
void tag_kernel(const float* __restrict__ hs, const float* __restrict__ W,
                const float* __restrict__ b, float* __restrict__ out)
{
  const int wave = threadIdx.x >> 6;
  const int lane = threadIdx.x & 63;
  const int t = blockIdx.x * 4 + wave;
  const float* hr = hs + (size_t)t * WHID;
  const float* wr = W + (size_t)lane * WHID;
  float acc = b[lane];
  for (int k = 0; k < WHID; k += 4) {
    float4 wv = *(const float4*)(wr + k);
    float4 hv = *(const float4*)(hr + k);
    acc = fmaf(wv.x, hv.x, acc);
    acc = fmaf(wv.y, hv.y, acc);
    acc = fmaf(wv.z, hv.z, acc);
    acc = fmaf(wv.w, hv.w, acc);
  }
  float m = acc;
#pragma unroll
  for (int off = 32; off > 0; off >>= 1) m = fmaxf(m, __shfl_xor(m, off));
  float e = __expf(acc - m);
  float sum = e;
#pragma unroll
  for (int off = 32; off > 0; off >>= 1) sum += __shfl_xor(sum, off);
  out[(size_t)t * NTAG + lane] = (acc - m) - __logf(sum);
}

extern "C" void kernel_launch(void* const* d_in, const int* in_sizes, int n_in,
                              void* d_out, int out_size, void* d_ws, size_t ws_size,
                              hipStream_t stream)
{
  const int* x          = (const int*)d_in[0];
  const int* chars      = (const int*)d_in[1];
  const int* lengths    = (const int*)d_in[2];
  const float* word_emb = (const float*)d_in[3];
  const float* char_emb = (const float*)d_in[4];
  const float* c_Wih    = (const float*)d_in[5];
  const float* c_Whh    = (const float*)d_in[6];
  const float* c_bih    = (const float*)d_in[7];
  const float* c_bhh    = (const float*)d_in[8];
  const float* w_Wih    = (const float*)d_in[9];
  const float* w_Whh    = (const float*)d_in[10];
  const float* w_bih    = (const float*)d_in[11];
  const float* w_bhh    = (const float*)d_in[12];
  const float* lin_W    = (const float*)d_in[13];
  const float* lin_b    = (const float*)d_in[14];
  float* out = (float*)d_out;

  char* ws = (char*)d_ws;
  // layout: [0,8192) hbuf (2x512 u64 tagged slots) | [8192,8704) cf_cnt[128]
  //         | [8704,9216) gx_cnt[128] | pad to 12288 | char_feat 4 MiB
  //         | Gx 64 MiB | hs 16 MiB   (total ~84 MiB)
  u64*   hbuf      = (u64*)ws;
  int*   cf_cnt    = (int*)(ws + 8192);
  int*   gx_cnt    = (int*)(ws + 8704);
  float* char_feat = (float*)(ws + 12288);
  float* Gx        = (float*)(ws + 12288 + (size_t)S_LEN * CHID * 4);
  float* hs        = (float*)(ws + 12288 + (size_t)S_LEN * CHID * 4
                                         + (size_t)S_LEN * GDIM * 4);

  // zero tags + tile counters every call (replay-safe)
  hipMemsetAsync(ws, 0, 12288, stream);

  fused_kernel<<<GRID_TOTAL, 256, 0, stream>>>(
      x, chars, lengths, word_emb, char_emb,
      c_Wih, c_Whh, c_bih, c_bhh,
      w_Wih, w_Whh, w_bih, w_bhh,
      char_feat, Gx, hs, hbuf, cf_cnt, gx_cnt);

  tag_kernel<<<S_LEN / 4, 256, 0, stream>>>(hs, lin_W, lin_b, out);
}